// Round 7
// baseline (447.372 us; speedup 1.0000x reference)
//
#include <hip/hip_runtime.h>
#include <hip/hip_bf16.h>

// Problem constants (fixed by reference)
#define NN 50000          // nodes
#define EE 800000         // edges (before self loops)
#define IN_DIM 128
#define HH 256            // HEADS*HID
#define HID 64
#define HEADS 4
#define OUT_DIM 64
#define SCAN_BLOCKS 196   // ceil(50000/256)
#define AGG_BLOCKS 1563   // agg2: waves = 6252, ~8 nodes/wave
#define TOTW (AGG_BLOCKS * 4)
#define FUSE_BLOCKS 1563  // ceil(50000/32) for fused agg1+gemm2

// bf16 helpers (round-to-nearest-even)
static __device__ __forceinline__ unsigned short f2bf(float f) {
    unsigned int u = __float_as_uint(f);
    u += 0x7fffu + ((u >> 16) & 1u);
    return (unsigned short)(u >> 16);
}
static __device__ __forceinline__ float bf2f(unsigned short h) {
    return __uint_as_float(((unsigned int)h) << 16);
}

// ---------------- CSR build ----------------

__global__ void hist_kernel(const int* __restrict__ ei, int* __restrict__ deg) {
    int e = blockIdx.x * 256 + threadIdx.x;   // grid covers exactly EE
    atomicAdd(&deg[ei[EE + e]], 1);
}

__global__ __launch_bounds__(256) void block_scan_kernel(
    const int* __restrict__ deg, int* __restrict__ local_scan,
    int* __restrict__ block_sum) {
    __shared__ int tmp[256];
    int t = threadIdx.x, i = blockIdx.x * 256 + t;
    int v = (i < NN) ? deg[i] : 0;
    tmp[t] = v;
    __syncthreads();
    for (int d = 1; d < 256; d <<= 1) {
        int u = (t >= d) ? tmp[t - d] : 0;
        __syncthreads();
        tmp[t] += u;
        __syncthreads();
    }
    if (i < NN) local_scan[i] = tmp[t] - v;    // exclusive within block
    if (t == 255) block_sum[blockIdx.x] = tmp[255];
}

__global__ __launch_bounds__(256) void scan_sums_kernel(int* __restrict__ block_sum) {
    __shared__ int tmp[256];
    int t = threadIdx.x;
    int v = (t < SCAN_BLOCKS) ? block_sum[t] : 0;
    tmp[t] = v;
    __syncthreads();
    for (int d = 1; d < 256; d <<= 1) {
        int u = (t >= d) ? tmp[t - d] : 0;
        __syncthreads();
        tmp[t] += u;
        __syncthreads();
    }
    if (t < SCAN_BLOCKS) block_sum[t] = tmp[t] - v;   // exclusive
}

__global__ __launch_bounds__(256) void finalize_kernel(
    const int* __restrict__ local_scan, const int* __restrict__ block_sum,
    int* __restrict__ row_ptr, int* __restrict__ cursor) {
    int i = blockIdx.x * 256 + threadIdx.x;
    if (i < NN) {
        int v = local_scan[i] + block_sum[blockIdx.x];
        row_ptr[i] = v; cursor[i] = v;
    }
    if (i == 0) row_ptr[NN] = EE;              // total degree is always EE
}

__global__ void scatter_kernel(const int* __restrict__ ei, int* __restrict__ cursor,
                               int* __restrict__ edge_src) {
    int e = blockIdx.x * 256 + threadIdx.x;
    int d = ei[EE + e];
    int pos = atomicAdd(&cursor[d], 1);
    edge_src[pos] = ei[e];
}

// ---------------- Layer 1 GEMM (R5 64-row structure): h1 = x @ W1 (bf16), fused dots ----
// 64-row tile, 4 waves x 16 rows; lane owns 4 consecutive cols (one head).

__global__ __launch_bounds__(256) void gemm1_kernel(
    const float* __restrict__ x, const float* __restrict__ W1,
    const float* __restrict__ a_src1, const float* __restrict__ a_dst1,
    unsigned short* __restrict__ h1, float* __restrict__ asrc1, float* __restrict__ adst1) {
    __shared__ __align__(16) float xs[64][IN_DIM];    // 32 KB
    int t = threadIdx.x;
    int row0 = blockIdx.x * 64;
    #pragma unroll
    for (int j = 0; j < 8; j++) {
        int idx = t + j * 256;                 // 2048 float4 total
        int r = idx >> 5, k4 = (idx & 31) * 4;
        int rr = row0 + r; if (rr >= NN) rr = NN - 1;
        *reinterpret_cast<float4*>(&xs[r][k4]) =
            *reinterpret_cast<const float4*>(&x[(size_t)rr * IN_DIM + k4]);
    }
    __syncthreads();
    int lane = t & 63, wid = t >> 6;
    float4 acc[16];
    #pragma unroll
    for (int r = 0; r < 16; r++) acc[r] = make_float4(0.f, 0.f, 0.f, 0.f);
    const float* wbase = W1 + lane * 4;
    for (int k = 0; k < IN_DIM; k += 4) {
        float4 w0 = *reinterpret_cast<const float4*>(&wbase[(k + 0) * HH]);
        float4 w1 = *reinterpret_cast<const float4*>(&wbase[(k + 1) * HH]);
        float4 w2 = *reinterpret_cast<const float4*>(&wbase[(k + 2) * HH]);
        float4 w3 = *reinterpret_cast<const float4*>(&wbase[(k + 3) * HH]);
        #pragma unroll
        for (int r = 0; r < 16; r++) {
            float4 xv = *reinterpret_cast<const float4*>(&xs[wid * 16 + r][k]); // broadcast
            acc[r].x = fmaf(xv.x, w0.x, acc[r].x); acc[r].y = fmaf(xv.x, w0.y, acc[r].y);
            acc[r].z = fmaf(xv.x, w0.z, acc[r].z); acc[r].w = fmaf(xv.x, w0.w, acc[r].w);
            acc[r].x = fmaf(xv.y, w1.x, acc[r].x); acc[r].y = fmaf(xv.y, w1.y, acc[r].y);
            acc[r].z = fmaf(xv.y, w1.z, acc[r].z); acc[r].w = fmaf(xv.y, w1.w, acc[r].w);
            acc[r].x = fmaf(xv.z, w2.x, acc[r].x); acc[r].y = fmaf(xv.z, w2.y, acc[r].y);
            acc[r].z = fmaf(xv.z, w2.z, acc[r].z); acc[r].w = fmaf(xv.z, w2.w, acc[r].w);
            acc[r].x = fmaf(xv.w, w3.x, acc[r].x); acc[r].y = fmaf(xv.w, w3.y, acc[r].y);
            acc[r].z = fmaf(xv.w, w3.z, acc[r].z); acc[r].w = fmaf(xv.w, w3.w, acc[r].w);
        }
    }
    float4 asv = *reinterpret_cast<const float4*>(&a_src1[lane * 4]);
    float4 adv = *reinterpret_cast<const float4*>(&a_dst1[lane * 4]);
    int head = lane >> 4;
    #pragma unroll
    for (int r = 0; r < 16; r++) {
        int row = row0 + wid * 16 + r;
        bool ok = row < NN;
        if (ok) {
            ushort4 hv;
            hv.x = f2bf(acc[r].x); hv.y = f2bf(acc[r].y);
            hv.z = f2bf(acc[r].z); hv.w = f2bf(acc[r].w);
            *reinterpret_cast<ushort4*>(&h1[(size_t)row * HH + lane * 4]) = hv;
        }
        float vs = acc[r].x * asv.x + acc[r].y * asv.y + acc[r].z * asv.z + acc[r].w * asv.w;
        float vd = acc[r].x * adv.x + acc[r].y * adv.y + acc[r].z * adv.z + acc[r].w * adv.w;
        #pragma unroll
        for (int o = 1; o < 16; o <<= 1) { vs += __shfl_xor(vs, o); vd += __shfl_xor(vd, o); }
        if (ok && (lane & 15) == 0) {
            asrc1[row * HEADS + head] = vs;
            adst1[row * HEADS + head] = vd;
        }
    }
}

// ---------------- FUSED: Layer-1 aggregation (+bias+ELU) -> LDS -> Layer-2 GEMM ------
// Block owns 32 consecutive nodes. Phase A: wave w aggregates nodes w*8..w*8+7,
// writing x2 rows into LDS (lane owns 4 channels). Phase B: gemm2 from LDS.

__global__ __launch_bounds__(256) void agg1_gemm2_kernel(
    const int* __restrict__ row_ptr, const int* __restrict__ edge_src,
    const unsigned short* __restrict__ h1, const float* __restrict__ asrc1,
    const float* __restrict__ adst1, const float* __restrict__ b1,
    const float* __restrict__ W2, const float* __restrict__ a_src2,
    const float* __restrict__ a_dst2,
    unsigned short* __restrict__ h2, float* __restrict__ asrc2, float* __restrict__ adst2) {
    __shared__ __align__(16) float xs[32][HH];        // 32 KB, x2 tile
    int t = threadIdx.x;
    int lane = t & 63, wid = t >> 6;
    int row0 = blockIdx.x * 32;
    int head = lane >> 4;
    unsigned cb = lane * 4;
    const unsigned short* h1l = h1 + cb;
    const float* asl = asrc1 + head;
    float4 bv = *reinterpret_cast<const float4*>(&b1[cb]);

    // ---- Phase A: aggregate 8 nodes per wave ----
    #pragma unroll 1
    for (int r = 0; r < 8; r++) {
        int node = row0 + wid * 8 + r;
        if (node < NN) {
            float ad = adst1[node * HEADS + head];
            int beg = row_ptr[node], end = row_ptr[node + 1];
            float denom = 0.f;
            float ax = 0.f, ay = 0.f, az = 0.f, aw = 0.f;
            int s0 = (beg < end) ? edge_src[beg] : node;
            int s1 = (beg + 1 < end) ? edge_src[beg + 1] : node;
            int s2 = (beg + 2 < end) ? edge_src[beg + 2] : node;
            float e0 = asl[(unsigned)s0 * HEADS];
            float e1 = asl[(unsigned)s1 * HEADS];
            float e2 = asl[(unsigned)s2 * HEADS];
            ushort4 h0 = *reinterpret_cast<const ushort4*>(&h1l[(unsigned)s0 * HH]);
            ushort4 h1v = *reinterpret_cast<const ushort4*>(&h1l[(unsigned)s1 * HH]);
            ushort4 h2v = *reinterpret_cast<const ushort4*>(&h1l[(unsigned)s2 * HH]);
            for (int i = beg; i <= end; i++) { // i==end -> self loop
                int j = i + 3;
                int s3 = (j < end) ? edge_src[j] : node;
                float e3 = asl[(unsigned)s3 * HEADS];
                ushort4 h3 = *reinterpret_cast<const ushort4*>(&h1l[(unsigned)s3 * HH]);
                float e = e0 + ad;
                e = fmaxf(e, 0.2f * e);        // LeakyReLU(0.2)
                float ex = __expf(e);
                denom += ex;
                ax = fmaf(ex, bf2f(h0.x), ax); ay = fmaf(ex, bf2f(h0.y), ay);
                az = fmaf(ex, bf2f(h0.z), az); aw = fmaf(ex, bf2f(h0.w), aw);
                e0 = e1; h0 = h1v;
                e1 = e2; h1v = h2v;
                e2 = e3; h2v = h3;
            }
            float inv = 1.0f / (denom + 1e-16f);
            float v0 = ax * inv + bv.x;
            float v1 = ay * inv + bv.y;
            float v2 = az * inv + bv.z;
            float v3 = aw * inv + bv.w;
            v0 = v0 > 0.f ? v0 : (__expf(v0) - 1.f);
            v1 = v1 > 0.f ? v1 : (__expf(v1) - 1.f);
            v2 = v2 > 0.f ? v2 : (__expf(v2) - 1.f);
            v3 = v3 > 0.f ? v3 : (__expf(v3) - 1.f);
            float4 o; o.x = v0; o.y = v1; o.z = v2; o.w = v3;
            *reinterpret_cast<float4*>(&xs[wid * 8 + r][cb]) = o;
        } else {
            float4 z = make_float4(0.f, 0.f, 0.f, 0.f);
            *reinterpret_cast<float4*>(&xs[wid * 8 + r][cb]) = z;
        }
    }
    __syncthreads();

    // ---- Phase B: h2 tile = xs @ W2, fused attention dots ----
    int c = lane;                               // col 0..63
    float acc[8];
    #pragma unroll
    for (int r = 0; r < 8; r++) acc[r] = 0.f;
    for (int k = 0; k < HH; k += 4) {
        float w0 = W2[(k + 0) * OUT_DIM + c];
        float w1 = W2[(k + 1) * OUT_DIM + c];
        float w2 = W2[(k + 2) * OUT_DIM + c];
        float w3 = W2[(k + 3) * OUT_DIM + c];
        #pragma unroll
        for (int r = 0; r < 8; r++) {
            float4 xv = *reinterpret_cast<const float4*>(&xs[wid * 8 + r][k]); // broadcast
            acc[r] = fmaf(xv.x, w0, acc[r]);
            acc[r] = fmaf(xv.y, w1, acc[r]);
            acc[r] = fmaf(xv.z, w2, acc[r]);
            acc[r] = fmaf(xv.w, w3, acc[r]);
        }
    }
    float as = a_src2[c], ad2v = a_dst2[c];
    #pragma unroll
    for (int r = 0; r < 8; r++) {
        int row = row0 + wid * 8 + r;
        bool ok = row < NN;
        if (ok) h2[(size_t)row * OUT_DIM + c] = f2bf(acc[r]);
        float vs = acc[r] * as, vd = acc[r] * ad2v;
        #pragma unroll
        for (int o = 32; o > 0; o >>= 1) { vs += __shfl_xor(vs, o); vd += __shfl_xor(vd, o); }
        if (ok && c == 0) { asrc2[row] = vs; adst2[row] = vd; }
    }
}

// ---------------- Layer 2 aggregation (final output): wave-batched, 3-deep ---------

__global__ __launch_bounds__(256) void agg2_kernel(
    const int* __restrict__ row_ptr, const int* __restrict__ edge_src,
    const unsigned short* __restrict__ h2, const float* __restrict__ asrc2,
    const float* __restrict__ adst2, const float* __restrict__ b2,
    float* __restrict__ out) {
    int wid = threadIdx.x >> 6, lane = threadIdx.x & 63;
    int gw = blockIdx.x * 4 + wid;
    const unsigned short* h2l = h2 + lane;
    float bl = b2[lane];
    for (int node = gw; node < NN; node += TOTW) {
        float ad = adst2[node];
        int beg = row_ptr[node], end = row_ptr[node + 1];
        float denom = 0.f, acc = 0.f;
        int s0 = (beg < end) ? edge_src[beg] : node;
        int s1 = (beg + 1 < end) ? edge_src[beg + 1] : node;
        int s2 = (beg + 2 < end) ? edge_src[beg + 2] : node;
        float e0 = asrc2[s0], e1 = asrc2[s1], e2 = asrc2[s2];
        unsigned short h0 = h2l[(unsigned)s0 * OUT_DIM];
        unsigned short h1v = h2l[(unsigned)s1 * OUT_DIM];
        unsigned short h2v = h2l[(unsigned)s2 * OUT_DIM];
        for (int i = beg; i <= end; i++) {
            int j = i + 3;
            int s3 = (j < end) ? edge_src[j] : node;
            float e3 = asrc2[s3];
            unsigned short h3 = h2l[(unsigned)s3 * OUT_DIM];
            float e = e0 + ad;
            e = fmaxf(e, 0.2f * e);
            float ex = __expf(e);
            denom += ex;
            acc = fmaf(ex, bf2f(h0), acc);
            e0 = e1; h0 = h1v;
            e1 = e2; h1v = h2v;
            e2 = e3; h2v = h3;
        }
        out[(size_t)node * OUT_DIM + lane] = acc / (denom + 1e-16f) + bl;
    }
}

// ---------------- launch ----------------

extern "C" void kernel_launch(void* const* d_in, const int* in_sizes, int n_in,
                              void* d_out, int out_size, void* d_ws, size_t ws_size,
                              hipStream_t stream) {
    const float* x   = (const float*)d_in[0];
    const int*   ei  = (const int*)d_in[1];
    const float* W1  = (const float*)d_in[2];
    const float* as1 = (const float*)d_in[3];
    const float* ad1 = (const float*)d_in[4];
    const float* b1  = (const float*)d_in[5];
    const float* W2  = (const float*)d_in[6];
    const float* as2 = (const float*)d_in[7];
    const float* ad2 = (const float*)d_in[8];
    const float* b2  = (const float*)d_in[9];
    float* out = (float*)d_out;

    char* ws = (char*)d_ws;
    size_t off = 0;
    auto alloc = [&](size_t bytes) -> void* {
        void* p = ws + off;
        off += (bytes + 255) & ~(size_t)255;
        return p;
    };
    unsigned short* h1 = (unsigned short*)alloc((size_t)NN * HH * 2);
    unsigned short* h2 = (unsigned short*)alloc((size_t)NN * OUT_DIM * 2);
    float* asrc1  = (float*)alloc((size_t)NN * HEADS * 4);
    float* adst1  = (float*)alloc((size_t)NN * HEADS * 4);
    float* asrc2  = (float*)alloc((size_t)NN * 4);
    float* adst2  = (float*)alloc((size_t)NN * 4);
    int*   deg    = (int*)alloc((size_t)NN * 4);
    int*   row_ptr= (int*)alloc((size_t)(NN + 1) * 4);
    int*   cursor = (int*)alloc((size_t)NN * 4);
    int*   edge_src=(int*)alloc((size_t)EE * 4);
    int*   local_scan = (int*)alloc((size_t)NN * 4);
    int*   block_sum  = (int*)alloc((size_t)SCAN_BLOCKS * 4);

    hipMemsetAsync(deg, 0, (size_t)NN * 4, stream);
    hist_kernel<<<EE / 256, 256, 0, stream>>>(ei, deg);
    block_scan_kernel<<<SCAN_BLOCKS, 256, 0, stream>>>(deg, local_scan, block_sum);
    scan_sums_kernel<<<1, 256, 0, stream>>>(block_sum);
    finalize_kernel<<<SCAN_BLOCKS, 256, 0, stream>>>(local_scan, block_sum, row_ptr, cursor);
    scatter_kernel<<<EE / 256, 256, 0, stream>>>(ei, cursor, edge_src);

    gemm1_kernel<<<(NN + 63) / 64, 256, 0, stream>>>(x, W1, as1, ad1, h1, asrc1, adst1);
    agg1_gemm2_kernel<<<FUSE_BLOCKS, 256, 0, stream>>>(
        row_ptr, edge_src, h1, asrc1, adst1, b1, W2, as2, ad2, h2, asrc2, adst2);
    agg2_kernel<<<AGG_BLOCKS, 256, 0, stream>>>(row_ptr, edge_src, h2, asrc2, adst2, b2, out);
}

// Round 8
// 396.898 us; speedup vs baseline: 1.1272x; 1.1272x over previous
//
#include <hip/hip_runtime.h>
#include <hip/hip_bf16.h>

// Problem constants (fixed by reference)
#define NN 50000          // nodes
#define EE 800000         // edges (before self loops)
#define IN_DIM 128
#define HH 256            // HEADS*HID
#define HID 64
#define HEADS 4
#define OUT_DIM 64
#define SCAN_BLOCKS 196   // ceil(50000/256)
#define G1_BLOCKS 782     // ceil(50000/64)
#define HIST_BLOCKS 3125  // EE/256
#define AGG_BLOCKS 1563   // waves = 6252, ~8 nodes/wave
#define TOTW (AGG_BLOCKS * 4)

// bf16 helpers (round-to-nearest-even)
static __device__ __forceinline__ unsigned short f2bf(float f) {
    unsigned int u = __float_as_uint(f);
    u += 0x7fffu + ((u >> 16) & 1u);
    return (unsigned short)(u >> 16);
}
static __device__ __forceinline__ float bf2f(unsigned short h) {
    return __uint_as_float(((unsigned int)h) << 16);
}

// ---------------- Layer 1 GEMM (64-row tile) + degree histogram, one dispatch ------
// blocks [0, G1_BLOCKS): 64-row GEMM tile; 4 waves x 16 rows; lane owns 4 cols (one head)
// blocks [G1_BLOCKS, ...): histogram over 256 edges each (fills idle CUs)

__global__ __launch_bounds__(256) void gemm1_hist_kernel(
    const float* __restrict__ x, const float* __restrict__ W1,
    const float* __restrict__ a_src1, const float* __restrict__ a_dst1,
    unsigned short* __restrict__ h1, float* __restrict__ asrc1, float* __restrict__ adst1,
    const int* __restrict__ ei, int* __restrict__ deg) {
    if (blockIdx.x >= G1_BLOCKS) {
        int e = (blockIdx.x - G1_BLOCKS) * 256 + threadIdx.x;
        atomicAdd(&deg[ei[EE + e]], 1);
        return;
    }
    __shared__ __align__(16) float xs[64][IN_DIM];    // 32 KB
    int t = threadIdx.x;
    int row0 = blockIdx.x * 64;
    #pragma unroll
    for (int j = 0; j < 8; j++) {
        int idx = t + j * 256;                 // 2048 float4 total
        int r = idx >> 5, k4 = (idx & 31) * 4;
        int rr = row0 + r; if (rr >= NN) rr = NN - 1;
        *reinterpret_cast<float4*>(&xs[r][k4]) =
            *reinterpret_cast<const float4*>(&x[(size_t)rr * IN_DIM + k4]);
    }
    __syncthreads();
    int lane = t & 63, wid = t >> 6;
    float4 acc[16];
    #pragma unroll
    for (int r = 0; r < 16; r++) acc[r] = make_float4(0.f, 0.f, 0.f, 0.f);
    const float* wbase = W1 + lane * 4;
    for (int k = 0; k < IN_DIM; k += 4) {
        float4 w0 = *reinterpret_cast<const float4*>(&wbase[(k + 0) * HH]);
        float4 w1 = *reinterpret_cast<const float4*>(&wbase[(k + 1) * HH]);
        float4 w2 = *reinterpret_cast<const float4*>(&wbase[(k + 2) * HH]);
        float4 w3 = *reinterpret_cast<const float4*>(&wbase[(k + 3) * HH]);
        #pragma unroll
        for (int r = 0; r < 16; r++) {
            float4 xv = *reinterpret_cast<const float4*>(&xs[wid * 16 + r][k]); // broadcast
            acc[r].x = fmaf(xv.x, w0.x, acc[r].x); acc[r].y = fmaf(xv.x, w0.y, acc[r].y);
            acc[r].z = fmaf(xv.x, w0.z, acc[r].z); acc[r].w = fmaf(xv.x, w0.w, acc[r].w);
            acc[r].x = fmaf(xv.y, w1.x, acc[r].x); acc[r].y = fmaf(xv.y, w1.y, acc[r].y);
            acc[r].z = fmaf(xv.y, w1.z, acc[r].z); acc[r].w = fmaf(xv.y, w1.w, acc[r].w);
            acc[r].x = fmaf(xv.z, w2.x, acc[r].x); acc[r].y = fmaf(xv.z, w2.y, acc[r].y);
            acc[r].z = fmaf(xv.z, w2.z, acc[r].z); acc[r].w = fmaf(xv.z, w2.w, acc[r].w);
            acc[r].x = fmaf(xv.w, w3.x, acc[r].x); acc[r].y = fmaf(xv.w, w3.y, acc[r].y);
            acc[r].z = fmaf(xv.w, w3.z, acc[r].z); acc[r].w = fmaf(xv.w, w3.w, acc[r].w);
        }
    }
    float4 asv = *reinterpret_cast<const float4*>(&a_src1[lane * 4]);
    float4 adv = *reinterpret_cast<const float4*>(&a_dst1[lane * 4]);
    int head = lane >> 4;
    #pragma unroll
    for (int r = 0; r < 16; r++) {
        int row = row0 + wid * 16 + r;
        bool ok = row < NN;
        if (ok) {
            ushort4 hv;
            hv.x = f2bf(acc[r].x); hv.y = f2bf(acc[r].y);
            hv.z = f2bf(acc[r].z); hv.w = f2bf(acc[r].w);
            *reinterpret_cast<ushort4*>(&h1[(size_t)row * HH + lane * 4]) = hv;
        }
        float vs = acc[r].x * asv.x + acc[r].y * asv.y + acc[r].z * asv.z + acc[r].w * asv.w;
        float vd = acc[r].x * adv.x + acc[r].y * adv.y + acc[r].z * adv.z + acc[r].w * adv.w;
        #pragma unroll
        for (int o = 1; o < 16; o <<= 1) { vs += __shfl_xor(vs, o); vd += __shfl_xor(vd, o); }
        if (ok && (lane & 15) == 0) {
            asrc1[row * HEADS + head] = vs;
            adst1[row * HEADS + head] = vd;
        }
    }
}

// ---------------- CSR scan chain ----------------

__global__ __launch_bounds__(256) void block_scan_kernel(
    const int* __restrict__ deg, int* __restrict__ local_scan,
    int* __restrict__ block_sum) {
    __shared__ int tmp[256];
    int t = threadIdx.x, i = blockIdx.x * 256 + t;
    int v = (i < NN) ? deg[i] : 0;
    tmp[t] = v;
    __syncthreads();
    for (int d = 1; d < 256; d <<= 1) {
        int u = (t >= d) ? tmp[t - d] : 0;
        __syncthreads();
        tmp[t] += u;
        __syncthreads();
    }
    if (i < NN) local_scan[i] = tmp[t] - v;    // exclusive within block
    if (t == 255) block_sum[blockIdx.x] = tmp[255];
}

__global__ __launch_bounds__(256) void scan_sums_kernel(int* __restrict__ block_sum) {
    __shared__ int tmp[256];
    int t = threadIdx.x;
    int v = (t < SCAN_BLOCKS) ? block_sum[t] : 0;
    tmp[t] = v;
    __syncthreads();
    for (int d = 1; d < 256; d <<= 1) {
        int u = (t >= d) ? tmp[t - d] : 0;
        __syncthreads();
        tmp[t] += u;
        __syncthreads();
    }
    if (t < SCAN_BLOCKS) block_sum[t] = tmp[t] - v;   // exclusive
}

__global__ __launch_bounds__(256) void finalize_kernel(
    const int* __restrict__ local_scan, const int* __restrict__ block_sum,
    int* __restrict__ row_ptr, int* __restrict__ cursor) {
    int i = blockIdx.x * 256 + threadIdx.x;
    if (i < NN) {
        int v = local_scan[i] + block_sum[blockIdx.x];
        row_ptr[i] = v; cursor[i] = v;
    }
    if (i == 0) row_ptr[NN] = EE;              // total degree is always EE
}

__global__ void scatter_kernel(const int* __restrict__ ei, int* __restrict__ cursor,
                               int* __restrict__ edge_src) {
    int e = blockIdx.x * 256 + threadIdx.x;
    int d = ei[EE + e];
    int pos = atomicAdd(&cursor[d], 1);
    edge_src[pos] = ei[e];
}

// ---------------- Layer 1 aggregation (+bias +ELU): wave-batched, 3-deep pipeline ----

__global__ __launch_bounds__(256) void agg1_kernel(
    const int* __restrict__ row_ptr, const int* __restrict__ edge_src,
    const unsigned short* __restrict__ h1, const float* __restrict__ asrc1,
    const float* __restrict__ adst1, const float* __restrict__ b1,
    float* __restrict__ x2) {
    int wid = threadIdx.x >> 6, lane = threadIdx.x & 63;
    int gw = blockIdx.x * 4 + wid;
    int head = lane >> 4;
    unsigned cb = lane * 4;
    const unsigned short* h1l = h1 + cb;       // per-lane channel base
    const float* asl = asrc1 + head;
    float4 bv = *reinterpret_cast<const float4*>(&b1[cb]);
    for (int node = gw; node < NN; node += TOTW) {
        float ad = adst1[node * HEADS + head];
        int beg = row_ptr[node], end = row_ptr[node + 1];
        float denom = 0.f;
        float ax = 0.f, ay = 0.f, az = 0.f, aw = 0.f;
        int s0 = (beg < end) ? edge_src[beg] : node;
        int s1 = (beg + 1 < end) ? edge_src[beg + 1] : node;
        int s2 = (beg + 2 < end) ? edge_src[beg + 2] : node;
        float e0 = asl[(unsigned)s0 * HEADS];
        float e1 = asl[(unsigned)s1 * HEADS];
        float e2 = asl[(unsigned)s2 * HEADS];
        ushort4 h0 = *reinterpret_cast<const ushort4*>(&h1l[(unsigned)s0 * HH]);
        ushort4 h1v = *reinterpret_cast<const ushort4*>(&h1l[(unsigned)s1 * HH]);
        ushort4 h2v = *reinterpret_cast<const ushort4*>(&h1l[(unsigned)s2 * HH]);
        for (int i = beg; i <= end; i++) {     // i==end -> self loop
            int j = i + 3;
            int s3 = (j < end) ? edge_src[j] : node;
            float e3 = asl[(unsigned)s3 * HEADS];
            ushort4 h3 = *reinterpret_cast<const ushort4*>(&h1l[(unsigned)s3 * HH]);
            float e = e0 + ad;
            e = fmaxf(e, 0.2f * e);            // LeakyReLU(0.2)
            float ex = __expf(e);
            denom += ex;
            ax = fmaf(ex, bf2f(h0.x), ax); ay = fmaf(ex, bf2f(h0.y), ay);
            az = fmaf(ex, bf2f(h0.z), az); aw = fmaf(ex, bf2f(h0.w), aw);
            e0 = e1; h0 = h1v;
            e1 = e2; h1v = h2v;
            e2 = e3; h2v = h3;
        }
        float inv = 1.0f / (denom + 1e-16f);
        float v0 = ax * inv + bv.x;
        float v1 = ay * inv + bv.y;
        float v2 = az * inv + bv.z;
        float v3 = aw * inv + bv.w;
        v0 = v0 > 0.f ? v0 : (__expf(v0) - 1.f);
        v1 = v1 > 0.f ? v1 : (__expf(v1) - 1.f);
        v2 = v2 > 0.f ? v2 : (__expf(v2) - 1.f);
        v3 = v3 > 0.f ? v3 : (__expf(v3) - 1.f);
        float4 o; o.x = v0; o.y = v1; o.z = v2; o.w = v3;
        *reinterpret_cast<float4*>(&x2[(size_t)node * HH + cb]) = o;
    }
}

// ---------------- Layer 2 GEMM: h2 = x2 @ W2 (bf16 out), fused dots ----------------
// 32-row tile; 4 waves x 8 rows; lane owns col `lane`; broadcast LDS reads.

__global__ __launch_bounds__(256) void gemm2_kernel(
    const float* __restrict__ x2, const float* __restrict__ W2,
    const float* __restrict__ a_src2, const float* __restrict__ a_dst2,
    unsigned short* __restrict__ h2, float* __restrict__ asrc2, float* __restrict__ adst2) {
    __shared__ __align__(16) float xs[32][HH];        // 32 KB
    int t = threadIdx.x;
    int row0 = blockIdx.x * 32;
    #pragma unroll
    for (int j = 0; j < 8; j++) {
        int idx = t + j * 256;                 // 2048 float4 total
        int r = idx >> 6, k4 = (idx & 63) * 4;
        int rr = row0 + r; if (rr >= NN) rr = NN - 1;
        *reinterpret_cast<float4*>(&xs[r][k4]) =
            *reinterpret_cast<const float4*>(&x2[(size_t)rr * HH + k4]);
    }
    __syncthreads();
    int c = t & 63, wid = t >> 6;
    float acc[8];
    #pragma unroll
    for (int r = 0; r < 8; r++) acc[r] = 0.f;
    for (int k = 0; k < HH; k += 4) {
        float w0 = W2[(k + 0) * OUT_DIM + c];
        float w1 = W2[(k + 1) * OUT_DIM + c];
        float w2 = W2[(k + 2) * OUT_DIM + c];
        float w3 = W2[(k + 3) * OUT_DIM + c];
        #pragma unroll
        for (int r = 0; r < 8; r++) {
            float4 xv = *reinterpret_cast<const float4*>(&xs[wid * 8 + r][k]); // broadcast
            acc[r] = fmaf(xv.x, w0, acc[r]);
            acc[r] = fmaf(xv.y, w1, acc[r]);
            acc[r] = fmaf(xv.z, w2, acc[r]);
            acc[r] = fmaf(xv.w, w3, acc[r]);
        }
    }
    float as = a_src2[c], ad = a_dst2[c];
    #pragma unroll
    for (int r = 0; r < 8; r++) {
        int row = row0 + wid * 8 + r;
        bool ok = row < NN;
        if (ok) h2[(size_t)row * OUT_DIM + c] = f2bf(acc[r]);
        float vs = acc[r] * as, vd = acc[r] * ad;
        #pragma unroll
        for (int o = 32; o > 0; o >>= 1) { vs += __shfl_xor(vs, o); vd += __shfl_xor(vd, o); }
        if (ok && c == 0) { asrc2[row] = vs; adst2[row] = vd; }
    }
}

// ---------------- Layer 2 aggregation (final output): wave-batched, 3-deep ---------

__global__ __launch_bounds__(256) void agg2_kernel(
    const int* __restrict__ row_ptr, const int* __restrict__ edge_src,
    const unsigned short* __restrict__ h2, const float* __restrict__ asrc2,
    const float* __restrict__ adst2, const float* __restrict__ b2,
    float* __restrict__ out) {
    int wid = threadIdx.x >> 6, lane = threadIdx.x & 63;
    int gw = blockIdx.x * 4 + wid;
    const unsigned short* h2l = h2 + lane;
    float bl = b2[lane];
    for (int node = gw; node < NN; node += TOTW) {
        float ad = adst2[node];
        int beg = row_ptr[node], end = row_ptr[node + 1];
        float denom = 0.f, acc = 0.f;
        int s0 = (beg < end) ? edge_src[beg] : node;
        int s1 = (beg + 1 < end) ? edge_src[beg + 1] : node;
        int s2 = (beg + 2 < end) ? edge_src[beg + 2] : node;
        float e0 = asrc2[s0], e1 = asrc2[s1], e2 = asrc2[s2];
        unsigned short h0 = h2l[(unsigned)s0 * OUT_DIM];
        unsigned short h1v = h2l[(unsigned)s1 * OUT_DIM];
        unsigned short h2v = h2l[(unsigned)s2 * OUT_DIM];
        for (int i = beg; i <= end; i++) {
            int j = i + 3;
            int s3 = (j < end) ? edge_src[j] : node;
            float e3 = asrc2[s3];
            unsigned short h3 = h2l[(unsigned)s3 * OUT_DIM];
            float e = e0 + ad;
            e = fmaxf(e, 0.2f * e);
            float ex = __expf(e);
            denom += ex;
            acc = fmaf(ex, bf2f(h0), acc);
            e0 = e1; h0 = h1v;
            e1 = e2; h1v = h2v;
            e2 = e3; h2v = h3;
        }
        out[(size_t)node * OUT_DIM + lane] = acc / (denom + 1e-16f) + bl;
    }
}

// ---------------- launch ----------------

extern "C" void kernel_launch(void* const* d_in, const int* in_sizes, int n_in,
                              void* d_out, int out_size, void* d_ws, size_t ws_size,
                              hipStream_t stream) {
    const float* x   = (const float*)d_in[0];
    const int*   ei  = (const int*)d_in[1];
    const float* W1  = (const float*)d_in[2];
    const float* as1 = (const float*)d_in[3];
    const float* ad1 = (const float*)d_in[4];
    const float* b1  = (const float*)d_in[5];
    const float* W2  = (const float*)d_in[6];
    const float* as2 = (const float*)d_in[7];
    const float* ad2 = (const float*)d_in[8];
    const float* b2  = (const float*)d_in[9];
    float* out = (float*)d_out;

    char* ws = (char*)d_ws;
    size_t off = 0;
    auto alloc = [&](size_t bytes) -> void* {
        void* p = ws + off;
        off += (bytes + 255) & ~(size_t)255;
        return p;
    };
    unsigned short* h1 = (unsigned short*)alloc((size_t)NN * HH * 2);
    float* x2     = (float*)alloc((size_t)NN * HH * 4);
    unsigned short* h2 = (unsigned short*)alloc((size_t)NN * OUT_DIM * 2);
    float* asrc1  = (float*)alloc((size_t)NN * HEADS * 4);
    float* adst1  = (float*)alloc((size_t)NN * HEADS * 4);
    float* asrc2  = (float*)alloc((size_t)NN * 4);
    float* adst2  = (float*)alloc((size_t)NN * 4);
    int*   deg    = (int*)alloc((size_t)NN * 4);
    int*   row_ptr= (int*)alloc((size_t)(NN + 1) * 4);
    int*   cursor = (int*)alloc((size_t)NN * 4);
    int*   edge_src=(int*)alloc((size_t)EE * 4);
    int*   local_scan = (int*)alloc((size_t)NN * 4);
    int*   block_sum  = (int*)alloc((size_t)SCAN_BLOCKS * 4);

    hipMemsetAsync(deg, 0, (size_t)NN * 4, stream);
    // 64-row gemm1 tiles + degree histogram in one dispatch
    gemm1_hist_kernel<<<G1_BLOCKS + HIST_BLOCKS, 256, 0, stream>>>(
        x, W1, as1, ad1, h1, asrc1, adst1, ei, deg);
    block_scan_kernel<<<SCAN_BLOCKS, 256, 0, stream>>>(deg, local_scan, block_sum);
    scan_sums_kernel<<<1, 256, 0, stream>>>(block_sum);
    finalize_kernel<<<SCAN_BLOCKS, 256, 0, stream>>>(local_scan, block_sum, row_ptr, cursor);
    scatter_kernel<<<EE / 256, 256, 0, stream>>>(ei, cursor, edge_src);

    agg1_kernel<<<AGG_BLOCKS, 256, 0, stream>>>(row_ptr, edge_src, h1, asrc1, adst1, b1, x2);
    gemm2_kernel<<<(NN + 31) / 32, 256, 0, stream>>>(x2, W2, as2, ad2, h2, asrc2, adst2);
    agg2_kernel<<<AGG_BLOCKS, 256, 0, stream>>>(row_ptr, edge_src, h2, asrc2, adst2, b2, out);
}

// Round 11
// 392.121 us; speedup vs baseline: 1.1409x; 1.0122x over previous
//
#include <hip/hip_runtime.h>
#include <hip/hip_bf16.h>

// Problem constants (fixed by reference)
#define NN 50000          // nodes
#define EE 800000         // edges (before self loops)
#define IN_DIM 128
#define HH 256            // HEADS*HID
#define HID 64
#define HEADS 4
#define OUT_DIM 64
#define SCAN_BLOCKS 196   // ceil(50000/256)
#define G1_BLOCKS 782     // ceil(50000/64)
#define SCAT_BLOCKS 3125  // EE/256
#define AGG_BLOCKS 3125   // waves = 12500 -> 4 nodes/wave, saturates 32 waves/CU
#define TOTW (AGG_BLOCKS * 4)

// bf16 helpers (round-to-nearest-even)
static __device__ __forceinline__ unsigned short f2bf(float f) {
    unsigned int u = __float_as_uint(f);
    u += 0x7fffu + ((u >> 16) & 1u);
    return (unsigned short)(u >> 16);
}
static __device__ __forceinline__ float bf2f(unsigned short h) {
    return __uint_as_float(((unsigned int)h) << 16);
}

// ---------------- CSR build ----------------

__global__ void hist_kernel(const int* __restrict__ ei, int* __restrict__ deg) {
    int e = blockIdx.x * 256 + threadIdx.x;   // grid covers exactly EE
    atomicAdd(&deg[ei[EE + e]], 1);
}

__global__ __launch_bounds__(256) void block_scan_kernel(
    const int* __restrict__ deg, int* __restrict__ local_scan,
    int* __restrict__ block_sum) {
    __shared__ int tmp[256];
    int t = threadIdx.x, i = blockIdx.x * 256 + t;
    int v = (i < NN) ? deg[i] : 0;
    tmp[t] = v;
    __syncthreads();
    for (int d = 1; d < 256; d <<= 1) {
        int u = (t >= d) ? tmp[t - d] : 0;
        __syncthreads();
        tmp[t] += u;
        __syncthreads();
    }
    if (i < NN) local_scan[i] = tmp[t] - v;    // exclusive within block
    if (t == 255) block_sum[blockIdx.x] = tmp[255];
}

__global__ __launch_bounds__(256) void scan_sums_kernel(int* __restrict__ block_sum) {
    __shared__ int tmp[256];
    int t = threadIdx.x;
    int v = (t < SCAN_BLOCKS) ? block_sum[t] : 0;
    tmp[t] = v;
    __syncthreads();
    for (int d = 1; d < 256; d <<= 1) {
        int u = (t >= d) ? tmp[t - d] : 0;
        __syncthreads();
        tmp[t] += u;
        __syncthreads();
    }
    if (t < SCAN_BLOCKS) block_sum[t] = tmp[t] - v;   // exclusive
}

__global__ __launch_bounds__(256) void finalize_kernel(
    const int* __restrict__ local_scan, const int* __restrict__ block_sum,
    int* __restrict__ row_ptr, int* __restrict__ cursor) {
    int i = blockIdx.x * 256 + threadIdx.x;
    if (i < NN) {
        int v = local_scan[i] + block_sum[blockIdx.x];
        row_ptr[i] = v; cursor[i] = v;
    }
    if (i == 0) row_ptr[NN] = EE;              // total degree is always EE
}

// ---------------- Layer 1 GEMM (64-row tile) + edge scatter, one dispatch ----------
// blocks [0, G1_BLOCKS): 64-row GEMM tile (4 waves x 16 rows; lane owns 4 cols).
// blocks [G1_BLOCKS, ...): CSR scatter over 256 edges each (overlaps with GEMM).
// Both only depend on inputs + finalize (cursor) — independent of each other.

__global__ __launch_bounds__(256) void gemm1_scatter_kernel(
    const float* __restrict__ x, const float* __restrict__ W1,
    const float* __restrict__ a_src1, const float* __restrict__ a_dst1,
    unsigned short* __restrict__ h1, float* __restrict__ asrc1, float* __restrict__ adst1,
    const int* __restrict__ ei, int* __restrict__ cursor, int* __restrict__ edge_src) {
    if (blockIdx.x >= G1_BLOCKS) {
        int e = (blockIdx.x - G1_BLOCKS) * 256 + threadIdx.x;
        int d = ei[EE + e];
        int pos = atomicAdd(&cursor[d], 1);
        edge_src[pos] = ei[e];
        return;
    }
    __shared__ __align__(16) float xs[64][IN_DIM];    // 32 KB
    int t = threadIdx.x;
    int row0 = blockIdx.x * 64;
    #pragma unroll
    for (int j = 0; j < 8; j++) {
        int idx = t + j * 256;                 // 2048 float4 total
        int r = idx >> 5, k4 = (idx & 31) * 4;
        int rr = row0 + r; if (rr >= NN) rr = NN - 1;
        *reinterpret_cast<float4*>(&xs[r][k4]) =
            *reinterpret_cast<const float4*>(&x[(size_t)rr * IN_DIM + k4]);
    }
    __syncthreads();
    int lane = t & 63, wid = t >> 6;
    float4 acc[16];
    #pragma unroll
    for (int r = 0; r < 16; r++) acc[r] = make_float4(0.f, 0.f, 0.f, 0.f);
    const float* wbase = W1 + lane * 4;
    for (int k = 0; k < IN_DIM; k += 4) {
        float4 w0 = *reinterpret_cast<const float4*>(&wbase[(k + 0) * HH]);
        float4 w1 = *reinterpret_cast<const float4*>(&wbase[(k + 1) * HH]);
        float4 w2 = *reinterpret_cast<const float4*>(&wbase[(k + 2) * HH]);
        float4 w3 = *reinterpret_cast<const float4*>(&wbase[(k + 3) * HH]);
        #pragma unroll
        for (int r = 0; r < 16; r++) {
            float4 xv = *reinterpret_cast<const float4*>(&xs[wid * 16 + r][k]); // broadcast
            acc[r].x = fmaf(xv.x, w0.x, acc[r].x); acc[r].y = fmaf(xv.x, w0.y, acc[r].y);
            acc[r].z = fmaf(xv.x, w0.z, acc[r].z); acc[r].w = fmaf(xv.x, w0.w, acc[r].w);
            acc[r].x = fmaf(xv.y, w1.x, acc[r].x); acc[r].y = fmaf(xv.y, w1.y, acc[r].y);
            acc[r].z = fmaf(xv.y, w1.z, acc[r].z); acc[r].w = fmaf(xv.y, w1.w, acc[r].w);
            acc[r].x = fmaf(xv.z, w2.x, acc[r].x); acc[r].y = fmaf(xv.z, w2.y, acc[r].y);
            acc[r].z = fmaf(xv.z, w2.z, acc[r].z); acc[r].w = fmaf(xv.z, w2.w, acc[r].w);
            acc[r].x = fmaf(xv.w, w3.x, acc[r].x); acc[r].y = fmaf(xv.w, w3.y, acc[r].y);
            acc[r].z = fmaf(xv.w, w3.z, acc[r].z); acc[r].w = fmaf(xv.w, w3.w, acc[r].w);
        }
    }
    float4 asv = *reinterpret_cast<const float4*>(&a_src1[lane * 4]);
    float4 adv = *reinterpret_cast<const float4*>(&a_dst1[lane * 4]);
    int head = lane >> 4;
    #pragma unroll
    for (int r = 0; r < 16; r++) {
        int row = row0 + wid * 16 + r;
        bool ok = row < NN;
        if (ok) {
            ushort4 hv;
            hv.x = f2bf(acc[r].x); hv.y = f2bf(acc[r].y);
            hv.z = f2bf(acc[r].z); hv.w = f2bf(acc[r].w);
            *reinterpret_cast<ushort4*>(&h1[(size_t)row * HH + lane * 4]) = hv;
        }
        float vs = acc[r].x * asv.x + acc[r].y * asv.y + acc[r].z * asv.z + acc[r].w * asv.w;
        float vd = acc[r].x * adv.x + acc[r].y * adv.y + acc[r].z * adv.z + acc[r].w * adv.w;
        #pragma unroll
        for (int o = 1; o < 16; o <<= 1) { vs += __shfl_xor(vs, o); vd += __shfl_xor(vd, o); }
        if (ok && (lane & 15) == 0) {
            asrc1[row * HEADS + head] = vs;
            adst1[row * HEADS + head] = vd;
        }
    }
}

// ---------------- Layer 1 aggregation (+bias +ELU): wave-batched, 3-deep pipeline ----

__global__ __launch_bounds__(256) void agg1_kernel(
    const int* __restrict__ row_ptr, const int* __restrict__ edge_src,
    const unsigned short* __restrict__ h1, const float* __restrict__ asrc1,
    const float* __restrict__ adst1, const float* __restrict__ b1,
    float* __restrict__ x2) {
    int wid = threadIdx.x >> 6, lane = threadIdx.x & 63;
    int gw = blockIdx.x * 4 + wid;
    int head = lane >> 4;
    unsigned cb = lane * 4;
    const unsigned short* h1l = h1 + cb;       // per-lane channel base
    const float* asl = asrc1 + head;
    float4 bv = *reinterpret_cast<const float4*>(&b1[cb]);
    for (int node = gw; node < NN; node += TOTW) {
        float ad = adst1[node * HEADS + head];
        int beg = row_ptr[node], end = row_ptr[node + 1];
        float denom = 0.f;
        float ax = 0.f, ay = 0.f, az = 0.f, aw = 0.f;
        int s0 = (beg < end) ? edge_src[beg] : node;
        int s1 = (beg + 1 < end) ? edge_src[beg + 1] : node;
        int s2 = (beg + 2 < end) ? edge_src[beg + 2] : node;
        float e0 = asl[(unsigned)s0 * HEADS];
        float e1 = asl[(unsigned)s1 * HEADS];
        float e2 = asl[(unsigned)s2 * HEADS];
        ushort4 h0 = *reinterpret_cast<const ushort4*>(&h1l[(unsigned)s0 * HH]);
        ushort4 h1v = *reinterpret_cast<const ushort4*>(&h1l[(unsigned)s1 * HH]);
        ushort4 h2v = *reinterpret_cast<const ushort4*>(&h1l[(unsigned)s2 * HH]);
        for (int i = beg; i <= end; i++) {     // i==end -> self loop
            int j = i + 3;
            int s3 = (j < end) ? edge_src[j] : node;
            float e3 = asl[(unsigned)s3 * HEADS];
            ushort4 h3 = *reinterpret_cast<const ushort4*>(&h1l[(unsigned)s3 * HH]);
            float e = e0 + ad;
            e = fmaxf(e, 0.2f * e);            // LeakyReLU(0.2)
            float ex = __expf(e);
            denom += ex;
            ax = fmaf(ex, bf2f(h0.x), ax); ay = fmaf(ex, bf2f(h0.y), ay);
            az = fmaf(ex, bf2f(h0.z), az); aw = fmaf(ex, bf2f(h0.w), aw);
            e0 = e1; h0 = h1v;
            e1 = e2; h1v = h2v;
            e2 = e3; h2v = h3;
        }
        float inv = 1.0f / (denom + 1e-16f);
        float v0 = ax * inv + bv.x;
        float v1 = ay * inv + bv.y;
        float v2 = az * inv + bv.z;
        float v3 = aw * inv + bv.w;
        v0 = v0 > 0.f ? v0 : (__expf(v0) - 1.f);
        v1 = v1 > 0.f ? v1 : (__expf(v1) - 1.f);
        v2 = v2 > 0.f ? v2 : (__expf(v2) - 1.f);
        v3 = v3 > 0.f ? v3 : (__expf(v3) - 1.f);
        float4 o; o.x = v0; o.y = v1; o.z = v2; o.w = v3;
        *reinterpret_cast<float4*>(&x2[(size_t)node * HH + cb]) = o;
    }
}

// ---------------- Layer 2 GEMM: h2 = x2 @ W2 (bf16 out), fused dots ----------------
// 32-row tile; 4 waves x 8 rows; lane owns col `lane`; broadcast LDS reads.

__global__ __launch_bounds__(256) void gemm2_kernel(
    const float* __restrict__ x2, const float* __restrict__ W2,
    const float* __restrict__ a_src2, const float* __restrict__ a_dst2,
    unsigned short* __restrict__ h2, float* __restrict__ asrc2, float* __restrict__ adst2) {
    __shared__ __align__(16) float xs[32][HH];        // 32 KB
    int t = threadIdx.x;
    int row0 = blockIdx.x * 32;
    #pragma unroll
    for (int j = 0; j < 8; j++) {
        int idx = t + j * 256;                 // 2048 float4 total
        int r = idx >> 6, k4 = (idx & 63) * 4;
        int rr = row0 + r; if (rr >= NN) rr = NN - 1;
        *reinterpret_cast<float4*>(&xs[r][k4]) =
            *reinterpret_cast<const float4*>(&x2[(size_t)rr * HH + k4]);
    }
    __syncthreads();
    int c = t & 63, wid = t >> 6;
    float acc[8];
    #pragma unroll
    for (int r = 0; r < 8; r++) acc[r] = 0.f;
    for (int k = 0; k < HH; k += 4) {
        float w0 = W2[(k + 0) * OUT_DIM + c];
        float w1 = W2[(k + 1) * OUT_DIM + c];
        float w2 = W2[(k + 2) * OUT_DIM + c];
        float w3 = W2[(k + 3) * OUT_DIM + c];
        #pragma unroll
        for (int r = 0; r < 8; r++) {
            float4 xv = *reinterpret_cast<const float4*>(&xs[wid * 8 + r][k]); // broadcast
            acc[r] = fmaf(xv.x, w0, acc[r]);
            acc[r] = fmaf(xv.y, w1, acc[r]);
            acc[r] = fmaf(xv.z, w2, acc[r]);
            acc[r] = fmaf(xv.w, w3, acc[r]);
        }
    }
    float as = a_src2[c], ad = a_dst2[c];
    #pragma unroll
    for (int r = 0; r < 8; r++) {
        int row = row0 + wid * 8 + r;
        bool ok = row < NN;
        if (ok) h2[(size_t)row * OUT_DIM + c] = f2bf(acc[r]);
        float vs = acc[r] * as, vd = acc[r] * ad;
        #pragma unroll
        for (int o = 32; o > 0; o >>= 1) { vs += __shfl_xor(vs, o); vd += __shfl_xor(vd, o); }
        if (ok && c == 0) { asrc2[row] = vs; adst2[row] = vd; }
    }
}

// ---------------- Layer 2 aggregation (final output): wave-batched, 3-deep ---------

__global__ __launch_bounds__(256) void agg2_kernel(
    const int* __restrict__ row_ptr, const int* __restrict__ edge_src,
    const unsigned short* __restrict__ h2, const float* __restrict__ asrc2,
    const float* __restrict__ adst2, const float* __restrict__ b2,
    float* __restrict__ out) {
    int wid = threadIdx.x >> 6, lane = threadIdx.x & 63;
    int gw = blockIdx.x * 4 + wid;
    const unsigned short* h2l = h2 + lane;
    float bl = b2[lane];
    for (int node = gw; node < NN; node += TOTW) {
        float ad = adst2[node];
        int beg = row_ptr[node], end = row_ptr[node + 1];
        float denom = 0.f, acc = 0.f;
        int s0 = (beg < end) ? edge_src[beg] : node;
        int s1 = (beg + 1 < end) ? edge_src[beg + 1] : node;
        int s2 = (beg + 2 < end) ? edge_src[beg + 2] : node;
        float e0 = asrc2[s0], e1 = asrc2[s1], e2 = asrc2[s2];
        unsigned short h0 = h2l[(unsigned)s0 * OUT_DIM];
        unsigned short h1v = h2l[(unsigned)s1 * OUT_DIM];
        unsigned short h2v = h2l[(unsigned)s2 * OUT_DIM];
        for (int i = beg; i <= end; i++) {
            int j = i + 3;
            int s3 = (j < end) ? edge_src[j] : node;
            float e3 = asrc2[s3];
            unsigned short h3 = h2l[(unsigned)s3 * OUT_DIM];
            float e = e0 + ad;
            e = fmaxf(e, 0.2f * e);
            float ex = __expf(e);
            denom += ex;
            acc = fmaf(ex, bf2f(h0), acc);
            e0 = e1; h0 = h1v;
            e1 = e2; h1v = h2v;
            e2 = e3; h2v = h3;
        }
        out[(size_t)node * OUT_DIM + lane] = acc / (denom + 1e-16f) + bl;
    }
}

// ---------------- launch ----------------

extern "C" void kernel_launch(void* const* d_in, const int* in_sizes, int n_in,
                              void* d_out, int out_size, void* d_ws, size_t ws_size,
                              hipStream_t stream) {
    const float* x   = (const float*)d_in[0];
    const int*   ei  = (const int*)d_in[1];
    const float* W1  = (const float*)d_in[2];
    const float* as1 = (const float*)d_in[3];
    const float* ad1 = (const float*)d_in[4];
    const float* b1  = (const float*)d_in[5];
    const float* W2  = (const float*)d_in[6];
    const float* as2 = (const float*)d_in[7];
    const float* ad2 = (const float*)d_in[8];
    const float* b2  = (const float*)d_in[9];
    float* out = (float*)d_out;

    char* ws = (char*)d_ws;
    size_t off = 0;
    auto alloc = [&](size_t bytes) -> void* {
        void* p = ws + off;
        off += (bytes + 255) & ~(size_t)255;
        return p;
    };
    unsigned short* h1 = (unsigned short*)alloc((size_t)NN * HH * 2);
    float* x2     = (float*)alloc((size_t)NN * HH * 4);
    unsigned short* h2 = (unsigned short*)alloc((size_t)NN * OUT_DIM * 2);
    float* asrc1  = (float*)alloc((size_t)NN * HEADS * 4);
    float* adst1  = (float*)alloc((size_t)NN * HEADS * 4);
    float* asrc2  = (float*)alloc((size_t)NN * 4);
    float* adst2  = (float*)alloc((size_t)NN * 4);
    int*   deg    = (int*)alloc((size_t)NN * 4);
    int*   row_ptr= (int*)alloc((size_t)(NN + 1) * 4);
    int*   cursor = (int*)alloc((size_t)NN * 4);
    int*   edge_src=(int*)alloc((size_t)EE * 4);
    int*   local_scan = (int*)alloc((size_t)NN * 4);
    int*   block_sum  = (int*)alloc((size_t)SCAN_BLOCKS * 4);

    hipMemsetAsync(deg, 0, (size_t)NN * 4, stream);
    // CSR chain first (doesn't wait on GEMM work)
    hist_kernel<<<EE / 256, 256, 0, stream>>>(ei, deg);
    block_scan_kernel<<<SCAN_BLOCKS, 256, 0, stream>>>(deg, local_scan, block_sum);
    scan_sums_kernel<<<1, 256, 0, stream>>>(block_sum);
    finalize_kernel<<<SCAN_BLOCKS, 256, 0, stream>>>(local_scan, block_sum, row_ptr, cursor);
    // gemm1 (independent) overlapped with scatter (needs finalize) in one dispatch
    gemm1_scatter_kernel<<<G1_BLOCKS + SCAT_BLOCKS, 256, 0, stream>>>(
        x, W1, as1, ad1, h1, asrc1, adst1, ei, cursor, edge_src);

    agg1_kernel<<<AGG_BLOCKS, 256, 0, stream>>>(row_ptr, edge_src, h1, asrc1, adst1, b1, x2);
    gemm2_kernel<<<(NN + 31) / 32, 256, 0, stream>>>(x2, W2, as2, ad2, h2, asrc2, adst2);
    agg2_kernel<<<AGG_BLOCKS, 256, 0, stream>>>(row_ptr, edge_src, h2, asrc2, adst2, b2, out);
}